// Round 3
// baseline (208.046 us; speedup 1.0000x reference)
//
#include <hip/hip_runtime.h>
#include <math.h>

// (B,S,D,C) = (64, 576, 768, 200)
#define Bsz  64
#define Ssz  576
#define Dsz  768
#define Csz  200
#define MT   48         // rows per block; grid 768 = exactly 3 blocks/CU, all co-resident
#define NKT  12         // K tiles of 64 floats

typedef float f32x4 __attribute__((ext_vector_type(4)));
typedef long  lx2   __attribute__((ext_vector_type(2)));

// one-time: W (200x768 fp32) -> fp8 e4m3 pre-swizzled into MFMA B-fragment order.
// Record (kt,t) = 1024 B at ((kt*13+t)*1024): lane l holds 16 B = [k2=0 8B][k2=1 8B],
// bytes = Wfp8[row = t*16 + (l&15)][col = kt*64 + k2*32 + ((l>>4)>>1)*16 + ((l>>4)&1)*8 ..+8].
// Logical row 200 = ones (rowsum trick), rows 201..207 = 0.
__global__ __launch_bounds__(256) void prep_w8(const float* __restrict__ W,
                                               unsigned long long* __restrict__ Wq) {
    const int i  = blockIdx.x * 256 + threadIdx.x;   // 12*13*64*2 = 19968 8-byte halves
    const int h  = i & 1;                            // k2
    const int j  = i >> 1;                           // (kt*13+t)*64 + l
    const int l  = j & 63;
    const int r2 = j >> 6;                           // kt*13 + t
    const int t  = r2 % 13;
    const int kt = r2 / 13;
    const int q  = l >> 4, m = l & 15;
    const int row = t * 16 + m;
    const int col = kt * 64 + h * 32 + ((q >> 1) << 4) + ((q & 1) << 3);
    unsigned long long v = 0ull;
    if (row < Csz) {
        const float4 a = *(const float4*)(W + (size_t)row * Dsz + col);
        const float4 b = *(const float4*)(W + (size_t)row * Dsz + col + 4);
        unsigned int lo = __builtin_amdgcn_cvt_pk_fp8_f32(a.x, a.y, 0u, false);
        lo = __builtin_amdgcn_cvt_pk_fp8_f32(a.z, a.w, lo, true);
        unsigned int hi = __builtin_amdgcn_cvt_pk_fp8_f32(b.x, b.y, 0u, false);
        hi = __builtin_amdgcn_cvt_pk_fp8_f32(b.z, b.w, hi, true);
        v = ((unsigned long long)hi << 32) | (unsigned long long)lo;
    } else if (row == Csz) {
        v = 0x3838383838383838ull;   // fp8 e4m3 1.0 x8
    }
    Wq[i] = v;
}

// global classifier runs FIRST: out[b,c] = ct[b]·gw[c] + gb[c]  (exact fp32)
__global__ __launch_bounds__(256) void gc_kernel(
    const float* __restrict__ ct, const float* __restrict__ gw,
    const float* __restrict__ gb, float* __restrict__ out) {
    const int b    = blockIdx.x;
    const int wv   = threadIdx.x >> 6;
    const int lane = threadIdx.x & 63;
    const int c    = blockIdx.y * 4 + wv;
    const float* wr = gw + (size_t)c * Dsz + lane * 12;
    const float* cr = ct + (size_t)b * Dsz + lane * 12;
    float s = 0.f;
#pragma unroll
    for (int j = 0; j < 3; ++j) {
        const float4 w = *(const float4*)(wr + 4 * j);
        const float4 x = *(const float4*)(cr + 4 * j);
        s += w.x * x.x + w.y * x.y + w.z * x.z + w.w * x.w;
    }
#pragma unroll
    for (int off = 32; off > 0; off >>= 1) s += __shfl_down(s, off, 64);
    if (lane == 0) out[b * Csz + c] = s + gb[c];
}

__device__ __forceinline__ long cvtA(const f32x4 lo, const f32x4 hi) {
    union { long l; unsigned int u[2]; } A;
    A.u[0] = __builtin_amdgcn_cvt_pk_fp8_f32(lo.x, lo.y, 0u, false);
    A.u[0] = __builtin_amdgcn_cvt_pk_fp8_f32(lo.z, lo.w, A.u[0], true);
    A.u[1] = __builtin_amdgcn_cvt_pk_fp8_f32(hi.x, hi.y, 0u, false);
    A.u[1] = __builtin_amdgcn_cvt_pk_fp8_f32(hi.z, hi.w, A.u[1], true);
    return A.l;
}

// One K-tile: W frags issued in 7+6 halves (caps live VGPRs), A cvt from the
// named set xs, then xs is refilled with tile KT+3 (WAR-safe: cvt precedes in
// program order; the vmcnt wait lands at first use, 3 bodies later).
template<int KT>
__device__ __forceinline__ void body(f32x4 (&xs)[4], const float* xp,
                                     const unsigned char* wp, f32x4 (&acc)[13]) {
    lx2 wfa[7];
#pragma unroll
    for (int t = 0; t < 7; ++t)
        wfa[t] = *(const lx2*)(wp + (size_t)(KT * 13 + t) * 1024);
    const long A0 = cvtA(xs[0], xs[1]);
    const long A1 = cvtA(xs[2], xs[3]);
    if (KT + 3 < NKT) {
#pragma unroll
        for (int j = 0; j < 4; ++j)
            xs[j] = *(const f32x4*)(xp + (KT + 3) * 64 + (j >> 1) * 32 + (j & 1) * 4);
    }
#pragma unroll
    for (int t = 0; t < 7; ++t) {
        acc[t] = __builtin_amdgcn_mfma_f32_16x16x32_fp8_fp8(A0, wfa[t][0], acc[t], 0, 0, 0);
        acc[t] = __builtin_amdgcn_mfma_f32_16x16x32_fp8_fp8(A1, wfa[t][1], acc[t], 0, 0, 0);
    }
    lx2 wfb[6];
#pragma unroll
    for (int t = 0; t < 6; ++t)
        wfb[t] = *(const lx2*)(wp + (size_t)(KT * 13 + 7 + t) * 1024);
#pragma unroll
    for (int t = 0; t < 6; ++t) {
        acc[7 + t] = __builtin_amdgcn_mfma_f32_16x16x32_fp8_fp8(A0, wfb[t][0], acc[7 + t], 0, 0, 0);
        acc[7 + t] = __builtin_amdgcn_mfma_f32_16x16x32_fp8_fp8(A1, wfb[t][1], acc[7 + t], 0, 0, 0);
    }
}

// Zero-LDS, zero-barrier, zero-scratch: X direct global->VGPR with depth-3
// pipeline over THREE NAMED register sets (all indices compile-time; no
// runtime-indexed arrays -> no scratch). W read as pre-swizzled coalesced
// dwordx4 fragments from L1/L2. 192 threads, grid 768, 3 blocks/CU.
__global__ __launch_bounds__(192, 3) void attn_kernel(
    const float* __restrict__ X,            // (B*S, D) fp32
    const unsigned char* __restrict__ Wq,   // swizzled fragments, 156 KB
    const float* __restrict__ attn_b,       // (C,)
    const float* __restrict__ lam,          // (1,)
    float* __restrict__ out)                // (B, C): gscore already written
{
    const int tid  = threadIdx.x;
    const int lane = tid & 63;
    const int w    = tid >> 6;      // 0..2
    const int m    = lane & 15;
    const int q    = lane >> 4;
    const int rowbase = blockIdx.x * MT;
    const int bidx    = blockIdx.x / 12;          // 12 blocks per batch, never crosses

    // A-fragment source: lane (q,m) of wave w owns row w*16+m,
    // k-floats kt*64 + k2*32 + q*8 .. +8  (verified layout)
    const float* xp = X + (size_t)(rowbase + w * 16 + m) * Dsz + q * 8;
    // B-fragment source: per-lane 16 B within each 1024-B record
    const unsigned char* wp = Wq + lane * 16;

    // depth-3 prefetch into named sets (kt mod 3 -> A,B,C)
    f32x4 xA[4], xB[4], xC[4];
#pragma unroll
    for (int j = 0; j < 4; ++j)
        xA[j] = *(const f32x4*)(xp + 0 * 64 + (j >> 1) * 32 + (j & 1) * 4);
#pragma unroll
    for (int j = 0; j < 4; ++j)
        xB[j] = *(const f32x4*)(xp + 1 * 64 + (j >> 1) * 32 + (j & 1) * 4);
#pragma unroll
    for (int j = 0; j < 4; ++j)
        xC[j] = *(const f32x4*)(xp + 2 * 64 + (j >> 1) * 32 + (j & 1) * 4);

    f32x4 acc[13];
#pragma unroll
    for (int t = 0; t < 13; ++t) acc[t] = (f32x4){0.f, 0.f, 0.f, 0.f};

    body<0>(xA, xp, wp, acc);
    body<1>(xB, xp, wp, acc);
    body<2>(xC, xp, wp, acc);
    body<3>(xA, xp, wp, acc);
    body<4>(xB, xp, wp, acc);
    body<5>(xC, xp, wp, acc);
    body<6>(xA, xp, wp, acc);
    body<7>(xB, xp, wp, acc);
    body<8>(xC, xp, wp, acc);
    body<9>(xA, xp, wp, acc);
    body<10>(xB, xp, wp, acc);
    body<11>(xC, xp, wp, acc);

    // rowsum via ones-column: tile 12, col 200 => m==8 lanes; row = q*4+r
    float rsv[4];
#pragma unroll
    for (int r = 0; r < 4; ++r) rsv[r] = __shfl(acc[12][r], (lane & 48) + 8, 64);

    const float scale = lam[0] * (1.f / ((float)Ssz * (float)Dsz));
    // epilogue: C/D col = lane&15, row = q*4+reg; reduce tile's 16 rows, atomic add
#pragma unroll
    for (int t = 0; t < 13; ++t) {
        const int c = t * 16 + m;
        if (c < Csz) {
            const float bias = attn_b[c];
            float s = 0.f;
#pragma unroll
            for (int r = 0; r < 4; ++r)
                s += rsv[r] / (1.f + __expf(-(acc[t][r] + bias)));
            s += __shfl_xor(s, 16, 64);
            s += __shfl_xor(s, 32, 64);
            if (q == 0) atomicAdd(&out[bidx * Csz + c], s * scale);
        }
    }
}

extern "C" void kernel_launch(void* const* d_in, const int* in_sizes, int n_in,
                              void* d_out, int out_size, void* d_ws, size_t ws_size,
                              hipStream_t stream) {
    const float* X   = (const float*)d_in[0];
    const float* ct  = (const float*)d_in[1];
    const float* aw  = (const float*)d_in[2];
    const float* ab  = (const float*)d_in[3];
    const float* gw  = (const float*)d_in[4];
    const float* gb  = (const float*)d_in[5];
    const float* lam = (const float*)d_in[6];
    float* out = (float*)d_out;
    unsigned long long* Wq = (unsigned long long*)d_ws;   // 12*13*1024 = 156 KB swizzled fp8

    prep_w8<<<(NKT * 13 * 64 * 2) / 256, 256, 0, stream>>>(aw, Wq);
    gc_kernel<<<dim3(Bsz, Csz / 4), 256, 0, stream>>>(ct, gw, gb, out);
    attn_kernel<<<(Bsz * Ssz) / MT, 192, 0, stream>>>(X, (const unsigned char*)Wq, ab, lam, out);
}